// Round 10
// baseline (716.496 us; speedup 1.0000x reference)
//
#include <hip/hip_runtime.h>
#include <hip/hip_bf16.h>
#include <stdint.h>

// HydraAttention: out[b,t,d] = q[b,t,d] * Skv[b,d] / sqrt(Sqq[b,d]*Skk[b,d])
// qkv = x@W + b. B=4 T=4096 D=2048. GEMM M=16384 N=6144 K=2048, bf16 MFMA.
// Round 10: r6's proven skeleton (builtin staging, 1 VMW(0)+BAR per 64-K tile,
// XOR swizzle, hoisted addressing) with MFMA shape switched to 32x32x16:
// +20% FLOP/cyc ceiling (2495 vs 2075 TF) and half the MFMA instructions.
// C/D layout (HW-verified m74/m101): col=lane&31, row=(reg&3)+8*(reg>>2)+4*(lane>>5).

#define DMODEL 2048
#define TSEQ   4096
#define MM     16384
#define NN     6144
#define KK     2048

typedef unsigned short u16;
typedef __bf16 bf16x8 __attribute__((ext_vector_type(8)));
typedef float  f32x16 __attribute__((ext_vector_type(16)));
typedef u16    u16x8  __attribute__((ext_vector_type(8)));

__device__ __forceinline__ u16 f2bf(float f) {
    unsigned u = __float_as_uint(f);
    u += 0x7fffu + ((u >> 16) & 1u);   // RNE
    return (u16)(u >> 16);
}
__device__ __forceinline__ float bf2f(u16 h) {
    return __uint_as_float(((unsigned)h) << 16);
}

// ---------------- pass 1a: x (f32) -> xb (bf16) ----------------
__global__ void cvt_x_kernel(const float* __restrict__ x, u16* __restrict__ xb) {
    long i = ((long)blockIdx.x * 256 + threadIdx.x) * 8;
    float4 a = *(const float4*)(x + i);
    float4 b = *(const float4*)(x + i + 4);
    u16x8 o;
    o[0] = f2bf(a.x); o[1] = f2bf(a.y); o[2] = f2bf(a.z); o[3] = f2bf(a.w);
    o[4] = f2bf(b.x); o[5] = f2bf(b.y); o[6] = f2bf(b.z); o[7] = f2bf(b.w);
    *(u16x8*)(xb + i) = o;
}

// ---------------- pass 1b: W (K x N f32) -> Wt (N x K bf16) ----------------
__global__ void cvt_wt_kernel(const float* __restrict__ W, u16* __restrict__ wt) {
    __shared__ u16 tile[64][65];
    const int k0 = blockIdx.x * 64;
    const int n0 = blockIdx.y * 64;
    const int t  = threadIdx.x;
#pragma unroll
    for (int p = 0; p < 16; ++p) {
        int idx = p * 256 + t;
        int kk = idx >> 6, nn = idx & 63;
        tile[kk][nn] = f2bf(W[(long)(k0 + kk) * NN + n0 + nn]);
    }
    __syncthreads();
#pragma unroll
    for (int p = 0; p < 16; ++p) {
        int idx = p * 256 + t;
        int nn = idx >> 6, kk = idx & 63;
        wt[(long)(n0 + nn) * KK + k0 + kk] = tile[kk][nn];
    }
}

// ---------------- pass 2: 256^2-tile 8-wave bf16 MFMA GEMM (32x32x16) ----------------
// A = xb (M x K), B = wt (N x K), k-contiguous. 512 threads = 8 waves (2M x 4N).
// Per wave: 128x64 output = 4 m-blocks x 2 n-blocks of 32x32; acc = 8 x f32x16.
// LDS: 2 dbuf x (A 256x64 + B 256x64) x 2B = 128 KiB. One VMW(0)+BAR per K-tile.
// Swizzle: phys chunk = logical ^ (row&7) (identical to r6; 2-way free on b128).

#define BAR()   __builtin_amdgcn_s_barrier()
#define VMW(n)  asm volatile("s_waitcnt vmcnt(" #n ")" ::: "memory")
#define PRIO(x) __builtin_amdgcn_s_setprio(x)

__global__ __launch_bounds__(512, 2) void gemm_qkv_32(
        const u16* __restrict__ xb, const u16* __restrict__ wt,
        const float* __restrict__ bias, float* __restrict__ qout,
        u16* __restrict__ kb, u16* __restrict__ vb) {
    __shared__ u16 smem[2][2][256 * 64];   // [buf][A/B][row*64 + elem] = 128 KiB

    const int tid = threadIdx.x;
    const int l = tid & 63, w = tid >> 6;
    const int wm = w >> 2, wn = w & 3;
    const int l31 = l & 31, lh = l >> 5, lkey = l & 7;

    // XCD-aware bijective swizzle (nwg = 1536, 1536 % 8 == 0)
    int bid = (int)blockIdx.x;
    int swz = (bid & 7) * 192 + (bid >> 3);
    const int m0 = (swz & 63) * 256;
    const int n0 = (swz >> 6) * 256;

    const int srow = w * 8 + (l >> 3); // staging row within a 64-row quarter
    const int sc8  = l & 7;            // staging 16B-chunk (linear LDS dest)

    // staging global sources, pre-swizzled: chunk ^ (row&7)
    const int cl = sc8 ^ (srow & 7);
    const u16* gA0 = xb + (long)(m0 +   0 + srow) * KK + cl * 8;
    const u16* gA1 = xb + (long)(m0 +  64 + srow) * KK + cl * 8;
    const u16* gA2 = xb + (long)(m0 + 128 + srow) * KK + cl * 8;
    const u16* gA3 = xb + (long)(m0 + 192 + srow) * KK + cl * 8;
    const u16* gB0 = wt + (long)(n0 +   0 + srow) * KK + cl * 8;
    const u16* gB1 = wt + (long)(n0 +  64 + srow) * KK + cl * 8;
    const u16* gB2 = wt + (long)(n0 + 128 + srow) * KK + cl * 8;
    const u16* gB3 = wt + (long)(n0 + 192 + srow) * KK + cl * 8;

    // hoisted read addressing (u16 elems). Read row r: r&7 == l31&7 == lkey
    // (all row bases are multiples of 32). chunk-class for k-step ks: ks*2+lh.
    const int abase = (wm * 128 + l31) * 64;
    const int bbase = (wn * 64  + l31) * 64;
    int ce[4];
#pragma unroll
    for (int ks = 0; ks < 4; ++ks) ce[ks] = ((ks * 2 + lh) ^ lkey) * 8;

    f32x16 acc[4][2] = {};
    bf16x8 Bf[2][4];

#define STG_(buf, mat, qq, gp) __builtin_amdgcn_global_load_lds(               \
    (__attribute__((address_space(1))) void*)(u16*)(gp),                       \
    (__attribute__((address_space(3))) void*)&smem[buf][mat][(qq)*4096 + w*512], 16, 0, 0)

#define STAGE_ALL(buf) do {                                                    \
    STG_(buf, 1, 0, gB0); STG_(buf, 1, 1, gB1);                                \
    STG_(buf, 1, 2, gB2); STG_(buf, 1, 3, gB3);                                \
    STG_(buf, 0, 0, gA0); STG_(buf, 0, 1, gA1);                                \
    STG_(buf, 0, 2, gA2); STG_(buf, 0, 3, gA3);                                \
    gA0 += 64; gA1 += 64; gA2 += 64; gA3 += 64;                                \
    gB0 += 64; gB1 += 64; gB2 += 64; gB3 += 64; } while (0)

#define RD_A(dst, cb, mi) do {                                                 \
    _Pragma("unroll")                                                          \
    for (int ks_ = 0; ks_ < 4; ++ks_)                                          \
        dst[ks_] = *(const bf16x8*)&smem[cb][0][abase + (mi) * 2048 + ce[ks_]];\
    } while (0)

#define MFMAQ(mi, Af)                                                          \
    PRIO(1);                                                                   \
    _Pragma("unroll")                                                          \
    for (int ks_ = 0; ks_ < 4; ++ks_) {                                        \
        _Pragma("unroll")                                                      \
        for (int ni_ = 0; ni_ < 2; ++ni_)                                      \
            acc[mi][ni_] = __builtin_amdgcn_mfma_f32_32x32x16_bf16(            \
                Af[ks_], Bf[ni_][ks_], acc[mi][ni_], 0, 0, 0);                 \
    }                                                                          \
    PRIO(0);

#define TILE(cb, nb, en_stage) do {                                            \
    if (en_stage) STAGE_ALL(nb);                                               \
    bf16x8 AfA[4], AfB[4];                                                     \
    _Pragma("unroll")                                                          \
    for (int ni_ = 0; ni_ < 2; ++ni_) {                                        \
        _Pragma("unroll")                                                      \
        for (int ks_ = 0; ks_ < 4; ++ks_)                                      \
            Bf[ni_][ks_] = *(const bf16x8*)&smem[cb][1][bbase + ni_ * 2048 + ce[ks_]]; \
    }                                                                          \
    RD_A(AfA, cb, 0); RD_A(AfB, cb, 1);                                        \
    MFMAQ(0, AfA)                                                              \
    RD_A(AfA, cb, 2);                                                          \
    MFMAQ(1, AfB)                                                              \
    RD_A(AfB, cb, 3);                                                          \
    MFMAQ(2, AfA)                                                              \
    MFMAQ(3, AfB)                                                              \
    VMW(0); BAR(); } while (0)

    // prologue: stage tile 0 into buf 0, land it.
    STAGE_ALL(0);
    VMW(0); BAR();

    for (int t = 0; t < 32; t += 2) {
        TILE(0, 1, true);          // tile t (stages t+1; t+1 <= 31 here)
        TILE(1, 0, (t + 2 < 32));  // tile t+1 (stages t+2 unless last)
    }

    // epilogue: + bias, route. C/D: col=lane&31, row=(reg&3)+8*(reg>>2)+4*lh.
    float bv[2];
#pragma unroll
    for (int ni_ = 0; ni_ < 2; ++ni_) bv[ni_] = bias[n0 + wn * 64 + ni_ * 32 + l31];

#pragma unroll
    for (int mi = 0; mi < 4; ++mi) {
#pragma unroll
        for (int ni_ = 0; ni_ < 2; ++ni_) {
            int gn = n0 + wn * 64 + ni_ * 32 + l31;
#pragma unroll
            for (int r = 0; r < 16; ++r) {
                int gm = m0 + wm * 128 + mi * 32 + (r & 3) + 8 * (r >> 2) + 4 * lh;
                float val = acc[mi][ni_][r] + bv[ni_];
                if (n0 < DMODEL) {
                    qout[(long)gm * DMODEL + gn] = val;
                } else if (n0 < 2 * DMODEL) {
                    kb[(long)gm * DMODEL + (gn - DMODEL)] = f2bf(val);
                } else {
                    vb[(long)gm * DMODEL + (gn - 2 * DMODEL)] = f2bf(val);
                }
            }
        }
    }
#undef STG_
#undef STAGE_ALL
#undef RD_A
#undef MFMAQ
#undef TILE
}

// ---------------- pass 3: per-(b,d) reductions Sqq, Skk, Skv ----------------
__global__ void reduce_kernel(const float* __restrict__ q, const u16* __restrict__ kb,
                              const u16* __restrict__ vb, float* __restrict__ sums) {
    const int b  = blockIdx.x >> 7;
    const int tc = blockIdx.x & 127;
    const long row0 = (long)b * TSEQ + tc * 32;
    const int d0 = threadIdx.x * 8;
    float aqq[8] = {}, akk[8] = {}, akv[8] = {};
    for (int r = 0; r < 32; ++r) {
        long base = (row0 + r) * (long)DMODEL + d0;
        float4 q0 = *(const float4*)(q + base);
        float4 q1 = *(const float4*)(q + base + 4);
        u16x8 k8 = *(const u16x8*)(kb + base);
        u16x8 v8 = *(const u16x8*)(vb + base);
        float qa[8] = {q0.x, q0.y, q0.z, q0.w, q1.x, q1.y, q1.z, q1.w};
#pragma unroll
        for (int j = 0; j < 8; ++j) {
            float kf = bf2f(k8[j]), vf = bf2f(v8[j]);
            aqq[j] += qa[j] * qa[j];
            akk[j] += kf * kf;
            akv[j] += kf * vf;
        }
    }
    const int sbase = b * DMODEL + d0;
#pragma unroll
    for (int j = 0; j < 8; ++j) {
        atomicAdd(&sums[sbase + j],         aqq[j]);
        atomicAdd(&sums[8192 + sbase + j],  akk[j]);
        atomicAdd(&sums[16384 + sbase + j], akv[j]);
    }
}

// ---------------- pass 4: s = Skv / sqrt(Sqq*Skk) ----------------
__global__ void finalize_kernel(const float* __restrict__ sums, float* __restrict__ s) {
    int i = blockIdx.x * 256 + threadIdx.x;
    float sqq = sums[i], skk = sums[8192 + i], skv = sums[16384 + i];
    s[i] = skv / sqrtf(sqq * skk);
}

// ---------------- pass 5: out *= s[b,d] ----------------
__global__ void scale_kernel(float* __restrict__ out, const float* __restrict__ s) {
    long e = ((long)blockIdx.x * 256 + threadIdx.x) * 4;
    int d = (int)(e & (DMODEL - 1));
    int b = (int)(e >> 23);
    float4 v  = *(float4*)(out + e);
    float4 sv = *(const float4*)(s + b * DMODEL + d);
    v.x *= sv.x; v.y *= sv.y; v.z *= sv.z; v.w *= sv.w;
    *(float4*)(out + e) = v;
}

extern "C" void kernel_launch(void* const* d_in, const int* in_sizes, int n_in,
                              void* d_out, int out_size, void* d_ws, size_t ws_size,
                              hipStream_t stream) {
    const float* x    = (const float*)d_in[0];
    const float* W    = (const float*)d_in[1];
    const float* bias = (const float*)d_in[2];
    float* out = (float*)d_out;

    char* ws = (char*)d_ws;
    u16*   xb   = (u16*)(ws);                         //  64 MiB
    u16*   wt   = (u16*)(ws + 67108864L);             //  24 MiB
    u16*   kb   = (u16*)(ws + 92274688L);             //  64 MiB
    u16*   vb   = (u16*)(ws + 159383552L);            //  64 MiB
    float* sums = (float*)(ws + 226492416L);          //  96 KiB
    float* sc   = (float*)(ws + 226492416L + 98304L); //  32 KiB

    hipMemsetAsync(sums, 0, 3 * 8192 * sizeof(float), stream);
    cvt_x_kernel<<<16384, 256, 0, stream>>>(x, xb);
    cvt_wt_kernel<<<dim3(KK / 64, NN / 64), 256, 0, stream>>>(W, wt);
    gemm_qkv_32<<<1536, 512, 0, stream>>>(xb, wt, bias, out, kb, vb);
    reduce_kernel<<<512, 256, 0, stream>>>(out, kb, vb, sums);
    finalize_kernel<<<32, 256, 0, stream>>>(sums, sc);
    scale_kernel<<<32768, 256, 0, stream>>>(out, sc);
}

// Round 12
// 533.414 us; speedup vs baseline: 1.3432x; 1.3432x over previous
//
#include <hip/hip_runtime.h>
#include <hip/hip_bf16.h>
#include <stdint.h>

// HydraAttention: out[b,t,d] = q[b,t,d] * Skv[b,d] / sqrt(Sqq[b,d]*Skk[b,d])
// qkv = x@W + b. B=4 T=4096 D=2048. GEMM M=16384 N=6144 K=2048, bf16 MFMA.
// Round 12 (= round 11 resubmitted after infra failure): r6 GEMM core (450 us)
// + pass fusion: q stored bf16; Sqq/Skk fused into GEMM epilogue; kv-only pass 3.

#define DMODEL 2048
#define TSEQ   4096
#define MM     16384
#define NN     6144
#define KK     2048

typedef unsigned short u16;
typedef __bf16 bf16x8 __attribute__((ext_vector_type(8)));
typedef float  f32x4  __attribute__((ext_vector_type(4)));
typedef u16    u16x8  __attribute__((ext_vector_type(8)));

__device__ __forceinline__ u16 f2bf(float f) {
    unsigned u = __float_as_uint(f);
    u += 0x7fffu + ((u >> 16) & 1u);   // RNE
    return (u16)(u >> 16);
}
__device__ __forceinline__ float bf2f(u16 h) {
    return __uint_as_float(((unsigned)h) << 16);
}

// ---------------- pass 1a: x (f32) -> xb (bf16) ----------------
__global__ void cvt_x_kernel(const float* __restrict__ x, u16* __restrict__ xb) {
    long i = ((long)blockIdx.x * 256 + threadIdx.x) * 8;
    float4 a = *(const float4*)(x + i);
    float4 b = *(const float4*)(x + i + 4);
    u16x8 o;
    o[0] = f2bf(a.x); o[1] = f2bf(a.y); o[2] = f2bf(a.z); o[3] = f2bf(a.w);
    o[4] = f2bf(b.x); o[5] = f2bf(b.y); o[6] = f2bf(b.z); o[7] = f2bf(b.w);
    *(u16x8*)(xb + i) = o;
}

// ---------------- pass 1b: W (K x N f32) -> Wt (N x K bf16) ----------------
__global__ void cvt_wt_kernel(const float* __restrict__ W, u16* __restrict__ wt) {
    __shared__ u16 tile[64][65];
    const int k0 = blockIdx.x * 64;
    const int n0 = blockIdx.y * 64;
    const int t  = threadIdx.x;
#pragma unroll
    for (int p = 0; p < 16; ++p) {
        int idx = p * 256 + t;
        int kk = idx >> 6, nn = idx & 63;
        tile[kk][nn] = f2bf(W[(long)(k0 + kk) * NN + n0 + nn]);
    }
    __syncthreads();
#pragma unroll
    for (int p = 0; p < 16; ++p) {
        int idx = p * 256 + t;
        int nn = idx >> 6, kk = idx & 63;
        wt[(long)(n0 + nn) * KK + k0 + kk] = tile[kk][nn];
    }
}

// ---------------- pass 2: 256^2-tile 8-wave bf16 MFMA GEMM (r6 core) ----------------
#define BAR()   __builtin_amdgcn_s_barrier()
#define VMW(n)  asm volatile("s_waitcnt vmcnt(" #n ")" ::: "memory")
#define PRIO(x) __builtin_amdgcn_s_setprio(x)

__global__ __launch_bounds__(512, 2) void gemm_qkv_pl(
        const u16* __restrict__ xb, const u16* __restrict__ wt,
        const float* __restrict__ bias, u16* __restrict__ qb,
        u16* __restrict__ kb, u16* __restrict__ vb, float* __restrict__ sums) {
    __shared__ u16 smem[2][2][256 * 64];   // [buf][A/B][row*64 + elem] = 128 KiB

    const int tid = threadIdx.x;
    const int l = tid & 63, w = tid >> 6;
    const int wm = w >> 2, wn = w & 3;
    const int lr = l & 15, lk = l >> 4;

    // XCD-aware bijective swizzle (nwg = 1536, 1536 % 8 == 0)
    int bid = (int)blockIdx.x;
    int swz = (bid & 7) * (1536 / 8) + (bid >> 3);
    const int m0 = (swz & 63) * 256;
    const int n0 = (swz >> 6) * 256;

    const int srow = w * 8 + (l >> 3);     // staging row within a 64-row quarter
    const int sc8  = l & 7;                // staging 16B-chunk (linear LDS dest)

    // hoisted read addressing (see r6): XORs loop-invariant
    const int cxor = lr & 7;
    const int aoff0 = (wm * 128 + lr) * 64 + ((0 + lk) ^ cxor) * 8;
    const int aoff1 = (wm * 128 + lr) * 64 + ((4 + lk) ^ cxor) * 8;
    const int boff0 = (wn * 64 + lr) * 64 + ((0 + lk) ^ cxor) * 8;
    const int boff1 = (wn * 64 + lr) * 64 + ((4 + lk) ^ cxor) * 8;

    const int cl = sc8 ^ (srow & 7);       // pre-swizzled global source chunk
    const u16* gA0 = xb + (long)(m0 +   0 + srow) * KK + cl * 8;
    const u16* gA1 = xb + (long)(m0 +  64 + srow) * KK + cl * 8;
    const u16* gA2 = xb + (long)(m0 + 128 + srow) * KK + cl * 8;
    const u16* gA3 = xb + (long)(m0 + 192 + srow) * KK + cl * 8;
    const u16* gB0 = wt + (long)(n0 +   0 + srow) * KK + cl * 8;
    const u16* gB1 = wt + (long)(n0 +  64 + srow) * KK + cl * 8;
    const u16* gB2 = wt + (long)(n0 + 128 + srow) * KK + cl * 8;
    const u16* gB3 = wt + (long)(n0 + 192 + srow) * KK + cl * 8;

    f32x4 acc[8][4] = {};

#define STG_(buf, mat, qq, gp) __builtin_amdgcn_global_load_lds(               \
    (__attribute__((address_space(1))) void*)(u16*)(gp),                       \
    (__attribute__((address_space(3))) void*)&smem[buf][mat][(qq)*4096 + w*512], 16, 0, 0)

#define STAGE_ALL(buf) do {                                                    \
    STG_(buf, 1, 0, gB0); STG_(buf, 1, 1, gB1);                                \
    STG_(buf, 1, 2, gB2); STG_(buf, 1, 3, gB3);                                \
    STG_(buf, 0, 0, gA0); STG_(buf, 0, 1, gA1);                                \
    STG_(buf, 0, 2, gA2); STG_(buf, 0, 3, gA3);                                \
    gA0 += 64; gA1 += 64; gA2 += 64; gA3 += 64;                                \
    gB0 += 64; gB1 += 64; gB2 += 64; gB3 += 64; } while (0)

#define RDA(dst, Ab, p) do {                                                   \
    dst[0][0] = *(const bf16x8*)(Ab + aoff0 + ((p) * 32 +  0) * 64);           \
    dst[0][1] = *(const bf16x8*)(Ab + aoff1 + ((p) * 32 +  0) * 64);           \
    dst[1][0] = *(const bf16x8*)(Ab + aoff0 + ((p) * 32 + 16) * 64);           \
    dst[1][1] = *(const bf16x8*)(Ab + aoff1 + ((p) * 32 + 16) * 64); } while (0)

#define MFMAQ(p, Af)                                                           \
    PRIO(1);                                                                   \
    _Pragma("unroll")                                                          \
    for (int i_ = 0; i_ < 2; ++i_) {                                           \
        _Pragma("unroll")                                                      \
        for (int n_ = 0; n_ < 4; ++n_) {                                       \
            acc[(p)*2+i_][n_] = __builtin_amdgcn_mfma_f32_16x16x32_bf16(       \
                Af[i_][0], Bf[n_][0], acc[(p)*2+i_][n_], 0, 0, 0);             \
            acc[(p)*2+i_][n_] = __builtin_amdgcn_mfma_f32_16x16x32_bf16(       \
                Af[i_][1], Bf[n_][1], acc[(p)*2+i_][n_], 0, 0, 0);             \
        } }                                                                    \
    PRIO(0);

#define TILE(cb, nb, en_stage) do {                                            \
    if (en_stage) STAGE_ALL(nb);                                               \
    const u16* Ab = &smem[cb][0][0];                                           \
    const u16* Bb = &smem[cb][1][0];                                           \
    bf16x8 Bf[4][2], Af0[2][2], Af1[2][2];                                     \
    _Pragma("unroll")                                                          \
    for (int n_ = 0; n_ < 4; ++n_) {                                           \
        Bf[n_][0] = *(const bf16x8*)(Bb + boff0 + n_ * 1024);                  \
        Bf[n_][1] = *(const bf16x8*)(Bb + boff1 + n_ * 1024);                  \
    }                                                                          \
    RDA(Af0, Ab, 0); RDA(Af1, Ab, 1);                                          \
    MFMAQ(0, Af0)                                                              \
    RDA(Af0, Ab, 2);                                                           \
    MFMAQ(1, Af1)                                                              \
    RDA(Af1, Ab, 3);                                                           \
    MFMAQ(2, Af0)                                                              \
    MFMAQ(3, Af1)                                                              \
    VMW(0); BAR(); } while (0)

    // prologue: stage tile 0 into buf 0, land it.
    STAGE_ALL(0);
    VMW(0); BAR();

    for (int t = 0; t < 32; t += 2) {
        TILE(0, 1, true);
        TILE(1, 0, (t + 2 < 32));
    }

    // ---- epilogue: + bias, route by region, fused Sqq/Skk partials ----
    // C/D: col=lane&15, row=(lane>>4)*4+reg.
    float bv[4];
#pragma unroll
    for (int n_ = 0; n_ < 4; ++n_) bv[n_] = bias[n0 + wn * 64 + n_ * 16 + lr];

    const bool isq = (n0 < DMODEL);
    const bool isk = (n0 >= DMODEL) && (n0 < 2 * DMODEL);
    float psum[4] = {0.f, 0.f, 0.f, 0.f};

#pragma unroll
    for (int mi = 0; mi < 8; ++mi) {
#pragma unroll
        for (int n_ = 0; n_ < 4; ++n_) {
            int gn = n0 + wn * 64 + n_ * 16 + lr;
#pragma unroll
            for (int j = 0; j < 4; ++j) {
                int gm = m0 + wm * 128 + mi * 16 + lk * 4 + j;
                float val = acc[mi][n_][j] + bv[n_];
                if (isq) {
                    qb[(long)gm * DMODEL + gn] = f2bf(val);
                    psum[n_] += val * val;
                } else if (isk) {
                    kb[(long)gm * DMODEL + (gn - DMODEL)] = f2bf(val);
                    psum[n_] += val * val;
                } else {
                    vb[(long)gm * DMODEL + (gn - 2 * DMODEL)] = f2bf(val);
                }
            }
        }
    }

    if (n0 < 2 * DMODEL) {      // q or k region: reduce partials, one atomic per gn
        const int roff = isq ? 0 : 8192;
        const int bb   = m0 >> 12;                 // batch (4096 rows each)
        const int dbase = (n0 - (isq ? 0 : DMODEL)) + wn * 64;
#pragma unroll
        for (int n_ = 0; n_ < 4; ++n_) {
            float v = psum[n_];
            v += __shfl_xor(v, 32);
            v += __shfl_xor(v, 16);                // lanes sharing lr now hold full
            if (lk == 0)
                atomicAdd(&sums[roff + bb * DMODEL + dbase + n_ * 16 + lr], v);
        }
    }
#undef STG_
#undef STAGE_ALL
#undef RDA
#undef MFMAQ
#undef TILE
}

// ---------------- pass 3: Skv = sum_t k*v (kv-only) ----------------
__global__ void kv_kernel(const u16* __restrict__ kb, const u16* __restrict__ vb,
                          float* __restrict__ sums) {
    const int b  = blockIdx.x >> 7;
    const int tc = blockIdx.x & 127;
    const long row0 = (long)b * TSEQ + tc * 32;
    const int d0 = threadIdx.x * 8;
    float akv[8] = {};
    for (int r = 0; r < 32; ++r) {
        long base = (row0 + r) * (long)DMODEL + d0;
        u16x8 k8 = *(const u16x8*)(kb + base);
        u16x8 v8 = *(const u16x8*)(vb + base);
#pragma unroll
        for (int j = 0; j < 8; ++j)
            akv[j] += bf2f(k8[j]) * bf2f(v8[j]);
    }
    const int sbase = b * DMODEL + d0;
#pragma unroll
    for (int j = 0; j < 8; ++j)
        atomicAdd(&sums[16384 + sbase + j], akv[j]);
}

// ---------------- pass 4: s = Skv / sqrt(Sqq*Skk) ----------------
__global__ void finalize_kernel(const float* __restrict__ sums, float* __restrict__ s) {
    int i = blockIdx.x * 256 + threadIdx.x;
    float sqq = sums[i], skk = sums[8192 + i], skv = sums[16384 + i];
    s[i] = skv / sqrtf(sqq * skk);
}

// ---------------- pass 5: out = bf2f(qb) * s[b,d] ----------------
__global__ void scale_kernel(const u16* __restrict__ qb, float* __restrict__ out,
                             const float* __restrict__ s) {
    long e = ((long)blockIdx.x * 256 + threadIdx.x) * 8;
    int d = (int)(e & (DMODEL - 1));
    int b = (int)(e >> 23);
    u16x8 q8 = *(const u16x8*)(qb + e);
    float4 s0 = *(const float4*)(s + b * DMODEL + d);
    float4 s1 = *(const float4*)(s + b * DMODEL + d + 4);
    float4 o0, o1;
    o0.x = bf2f(q8[0]) * s0.x; o0.y = bf2f(q8[1]) * s0.y;
    o0.z = bf2f(q8[2]) * s0.z; o0.w = bf2f(q8[3]) * s0.w;
    o1.x = bf2f(q8[4]) * s1.x; o1.y = bf2f(q8[5]) * s1.y;
    o1.z = bf2f(q8[6]) * s1.z; o1.w = bf2f(q8[7]) * s1.w;
    *(float4*)(out + e) = o0;
    *(float4*)(out + e + 4) = o1;
}

extern "C" void kernel_launch(void* const* d_in, const int* in_sizes, int n_in,
                              void* d_out, int out_size, void* d_ws, size_t ws_size,
                              hipStream_t stream) {
    const float* x    = (const float*)d_in[0];
    const float* W    = (const float*)d_in[1];
    const float* bias = (const float*)d_in[2];
    float* out = (float*)d_out;

    char* ws = (char*)d_ws;
    u16*   xb   = (u16*)(ws);                         //  64 MiB
    u16*   wt   = (u16*)(ws + 67108864L);             //  24 MiB
    u16*   kb   = (u16*)(ws + 92274688L);             //  64 MiB
    u16*   vb   = (u16*)(ws + 159383552L);            //  64 MiB
    u16*   qb   = (u16*)(ws + 226492416L);            //  64 MiB
    float* sums = (float*)(ws + 293601280L);          //  96 KiB
    float* sc   = (float*)(ws + 293601280L + 98304L); //  32 KiB

    hipMemsetAsync(sums, 0, 3 * 8192 * sizeof(float), stream);
    cvt_x_kernel<<<16384, 256, 0, stream>>>(x, xb);
    cvt_wt_kernel<<<dim3(KK / 64, NN / 64), 256, 0, stream>>>(W, wt);
    gemm_qkv_pl<<<1536, 512, 0, stream>>>(xb, wt, bias, qb, kb, vb, sums);
    kv_kernel<<<512, 256, 0, stream>>>(kb, vb, sums);
    finalize_kernel<<<32, 256, 0, stream>>>(sums, sc);
    scale_kernel<<<16384, 256, 0, stream>>>(qb, out, sc);
}